// Round 11
// baseline (174.379 us; speedup 1.0000x reference)
//
#include <hip/hip_runtime.h>
#include <math.h>

#define N_PTS   8192
#define KNN     30
#define CAPG    104     // max stored candidates per group (lambda=48, +8 sigma)
#define STR     105     // LDS row stride in u64
#define GROUPS  8       // queries per block
#define BLOCK   128     // 2 waves per block
#define NZ      64
#define NY      64
#define NBKT    (NZ * NY)
#define CLO     -4.0f
#define CSC     8.0f    // bucket = floor((c - CLO) * CSC)
#define LAMBDA  48.0f

// ws: S f4[32768]@0 | O i32[32768]@524288 | bstart i32[4*4097]@655360
//     hist i32[4*4096]@720912 | cur i32[4*4096]@786448

__device__ __forceinline__ int clampi(int v, int lo, int hi) {
    return v < lo ? lo : (v > hi ? hi : v);
}
__device__ __forceinline__ int bucket_of(float pz, float py) {
    int zb = clampi((int)floorf((pz - CLO) * CSC), 0, NZ - 1);
    int yb = clampi((int)floorf((py - CLO) * CSC), 0, NY - 1);
    return (zb << 6) | yb;
}

// ---------------------------------------------------------------------------
// Hist + out ch0..2 copy. 128 blocks x 256.
// ---------------------------------------------------------------------------
__global__ __launch_bounds__(256) void hist_kernel(const float* __restrict__ x,
                                                   int* __restrict__ hist,
                                                   float* __restrict__ out) {
    int gid = blockIdx.x * 256 + threadIdx.x;       // 0..32767
    int b = gid >> 13, i = gid & (N_PTS - 1);
    const float* xb = x + (size_t)b * 3 * N_PTS;
    float px = xb[i], py = xb[N_PTS + i], pz = xb[2 * N_PTS + i];
    float* ob = out + (size_t)b * 6 * N_PTS;
    ob[i]             = px;
    ob[N_PTS + i]     = py;
    ob[2 * N_PTS + i] = pz;
    atomicAdd(&hist[b * NBKT + bucket_of(pz, py)], 1);
}

// ---------------------------------------------------------------------------
// Per-batch prefix scan over 4096 buckets. 4 blocks (one per batch) x 256.
// ---------------------------------------------------------------------------
__global__ __launch_bounds__(256) void scan_kernel(const int* __restrict__ hist,
                                                   int* __restrict__ bstart,
                                                   int* __restrict__ cur) {
    __shared__ int wtot[4];
    const int b = blockIdx.x, t = threadIdx.x;
    const int lane = t & 63, wid = t >> 6;
    const int* h = hist + b * NBKT;
    int base = t * 16;                              // 256 threads x 16 buckets
    int s = 0;
    #pragma unroll
    for (int k = 0; k < 16; ++k) s += h[base + k];
    int sum = s;
    #pragma unroll
    for (int off = 1; off < 64; off <<= 1) {
        int v = __shfl_up(sum, off);
        if (lane >= off) sum += v;
    }
    if (lane == 63) wtot[wid] = sum;
    __syncthreads();
    int wbase = 0;
    #pragma unroll
    for (int k = 0; k < 4; ++k) wbase += (k < wid) ? wtot[k] : 0;
    int run = wbase + sum - s;                      // exclusive prefix
    int* bsb = bstart + b * (NBKT + 1);
    #pragma unroll
    for (int k = 0; k < 16; ++k) {
        bsb[base + k] = run;
        cur[b * NBKT + base + k] = run;
        run += h[base + k];
    }
    if (t == 255) bsb[NBKT] = N_PTS;
}

// ---------------------------------------------------------------------------
// Counting-sort scatter (xx_np = bitwise-numpy |p|^2). 128 blocks x 256.
// ---------------------------------------------------------------------------
__global__ __launch_bounds__(256) void scatter_kernel(const float* __restrict__ x,
                                                      float4* __restrict__ S,
                                                      int* __restrict__ O,
                                                      int* __restrict__ cur) {
    int gid = blockIdx.x * 256 + threadIdx.x;       // 0..32767
    int b = gid >> 13, i = gid & (N_PTS - 1);
    const float* xb = x + (size_t)b * 3 * N_PTS;
    float px = xb[i], py = xb[N_PTS + i], pz = xb[2 * N_PTS + i];
    float xx = __fadd_rn(__fadd_rn(__fmul_rn(px, px), __fmul_rn(py, py)),
                         __fmul_rn(pz, pz));
    int dst = atomicAdd(&cur[b * NBKT + bucket_of(pz, py)], 1);
    S[(b << 13) + dst] = make_float4(px, py, pz, xx);
    O[(b << 13) + dst] = i;
}

// ---------------------------------------------------------------------------
// Main: 16 lanes/query, 8 queries/block, STRATIFIED qid = qblk + g*4096 so each
// block's 8 queries sample the full density range (uniform block cost).
// ---------------------------------------------------------------------------
__global__ __launch_bounds__(BLOCK, 6) void knn_normal_kernel(const float4* __restrict__ S,
                                                              const int* __restrict__ O,
                                                              const int* __restrict__ bstart,
                                                              float* __restrict__ out) {
    __shared__ unsigned long long ldk[GROUPS * STR];

    const int t    = threadIdx.x;
    const int l16  = t & 15;
    const int g    = t >> 4;
    const int gsh  = (t & 63) & ~15;
    const int qid  = blockIdx.x + (g << 12);       // stratified (bijective)
    const int b    = qid >> 13;
    const int pos  = qid & (N_PTS - 1);
    const float4* __restrict__ P  = S + ((size_t)b << 13);
    const int*    __restrict__ Ob = O + ((size_t)b << 13);
    const int*    __restrict__ bs = bstart + b * (NBKT + 1);
    const float4 qp = P[pos];
    const int    oi = Ob[pos];

    unsigned long long* __restrict__ ldg = ldk + g * STR;

    // ---- radius: solve lambda(r)=48 (Gaussian ball mass), lane-parallel Simpson-9
    const float c = fmaxf(sqrtf(qp.w), 1e-3f);
    float rlo = 0.05f, rhi = 6.0f;
    for (int it = 0; it < 14; ++it) {
        float r = 0.5f * (rlo + rhi);
        float slo = fmaxf(c - r, 0.0f);
        float h = (c + r - slo) * 0.125f;
        float f = 0.0f;
        if (l16 <= 8) {
            float sq = slo + h * (float)l16;
            float cs = c - sq;
            float hh = fmaxf(fminf((r * r - cs * cs) * (0.5f / c), 2.0f * sq), 0.0f);
            float w = (l16 == 0 || l16 == 8) ? 1.0f : ((l16 & 1) ? 4.0f : 2.0f);
            f = w * __expf(-0.5f * sq * sq) * sq * hh;
        }
        f += __shfl_xor(f, 1, 16); f += __shfl_xor(f, 2, 16);
        f += __shfl_xor(f, 4, 16); f += __shfl_xor(f, 8, 16);
        float lam = 1089.3f * f * h;       // 520.1 * 2*pi / 3
        if (lam < LAMBDA) rlo = r; else rhi = r;
    }
    float rad = rhi * 1.02f;
    float r2  = rad * rad;

    int  cnt = 0;
    bool active = true;

    for (;;) {
        if (active) {
            cnt = 0;
            float w = __fmaf_rn(sqrtf(r2), 1.002f, 1e-3f);   // guard band
            int zlo = clampi((int)floorf((qp.z - w - CLO) * CSC), 0, NZ - 1);
            int zhi = clampi((int)floorf((qp.z + w - CLO) * CSC), 0, NZ - 1);
            int ylo = clampi((int)floorf((qp.y - w - CLO) * CSC), 0, NY - 1);
            int yhi = clampi((int)floorf((qp.y + w - CLO) * CSC), 0, NY - 1);
            for (int zb = zlo; zb <= zhi; ++zb) {
                int lo = bs[(zb << 6) + ylo];
                int hi = bs[(zb << 6) + yhi + 1];
                int smax = (hi - lo + 31) >> 5;   // group-uniform, 32 cand/iter
                for (int s = 0; s < smax; ++s) {
                    int j1  = lo + (s << 5) + l16;
                    int j2  = j1 + 16;
                    int jc1 = j1 < hi ? j1 : hi - 1;
                    int jc2 = j2 < hi ? j2 : hi - 1;
                    float4 p1 = P[jc1];
                    float4 p2 = P[jc2];
                    // bitwise numpy-fp32 pairwise distances
                    float mm1 = __fmaf_rn(qp.z, p1.z, __fmaf_rn(qp.y, p1.y, __fmul_rn(qp.x, p1.x)));
                    float d1  = __fsub_rn(__fadd_rn(qp.w, p1.w), __fmul_rn(2.0f, mm1));
                    float mm2 = __fmaf_rn(qp.z, p2.z, __fmaf_rn(qp.y, p2.y, __fmul_rn(qp.x, p2.x)));
                    float d2  = __fsub_rn(__fadd_rn(qp.w, p2.w), __fmul_rn(2.0f, mm2));
                    bool hit1 = (j1 < hi) && (d1 <= r2);
                    bool hit2 = (j2 < hi) && (d2 <= r2);
                    unsigned long long m1 = __ballot(hit1);
                    unsigned sub1 = (unsigned)((m1 >> gsh) & 0xFFFFull);
                    if (hit1) {
                        int slot = cnt + __popc(sub1 & ((1u << l16) - 1u));
                        if (slot < CAPG) {
                            unsigned u = __float_as_uint(d1);
                            u = (u & 0x80000000u) ? ~u : (u | 0x80000000u);
                            ldg[slot] = ((unsigned long long)u << 28) | (unsigned long long)jc1;
                        }
                    }
                    cnt += __popc(sub1);
                    unsigned long long m2 = __ballot(hit2);
                    unsigned sub2 = (unsigned)((m2 >> gsh) & 0xFFFFull);
                    if (hit2) {
                        int slot = cnt + __popc(sub2 & ((1u << l16) - 1u));
                        if (slot < CAPG) {
                            unsigned u = __float_as_uint(d2);
                            u = (u & 0x80000000u) ? ~u : (u | 0x80000000u);
                            ldg[slot] = ((unsigned long long)u << 28) | (unsigned long long)jc2;
                        }
                    }
                    cnt += __popc(sub2);
                }
            }
        }
        bool bad = active && (cnt < KNN || cnt > CAPG);
        if (__ballot(bad) == 0ULL) break;         // wave-uniform exit
        active = bad;
        if (active) r2 = (cnt < KNN) ? r2 * 1.6f : r2 * 0.82f;
    }

    // fill orig-idx field (bits 14..27) so u64 order == lex (d, orig idx)
    for (int k = l16; k < cnt; k += 16) {
        unsigned long long key = ldg[k];
        int jc = (int)(key & 0x3FFFull);
        ldg[k] = (key & ~0x0FFFFFFFull) | ((unsigned long long)Ob[jc] << 14) | (unsigned long long)jc;
    }
    __syncthreads();

    // ---- stable top-30: rank by u64 key (keys unique) ----
    const double qx = (double)qp.x, qy = (double)qp.y, qz = (double)qp.z;
    double sx = 0.0, sy = 0.0, sz = 0.0;
    double sxx = 0.0, sxy = 0.0, sxz = 0.0, syy = 0.0, syz = 0.0, szz = 0.0;

    for (int k = l16; k < cnt; k += 16) {
        unsigned long long key = ldg[k];
        int rank = 0;
        for (int u = 0; u < cnt; ++u) rank += (ldg[u] < key) ? 1 : 0;
        if (rank < KNN) {                         // exactly 30 survivors
            float4 p = P[(int)(key & 0x3FFFull)];
            double ax = (double)p.x - qx, ay = (double)p.y - qy, az = (double)p.z - qz;
            sx += ax; sy += ay; sz += az;
            sxx = fma(ax, ax, sxx); sxy = fma(ax, ay, sxy); sxz = fma(ax, az, sxz);
            syy = fma(ay, ay, syy); syz = fma(ay, az, syz); szz = fma(az, az, szz);
        }
    }

    #pragma unroll
    for (int off = 1; off < 16; off <<= 1) {
        sx  += __shfl_xor(sx,  off, 16); sy  += __shfl_xor(sy,  off, 16); sz  += __shfl_xor(sz,  off, 16);
        sxx += __shfl_xor(sxx, off, 16); sxy += __shfl_xor(sxy, off, 16); sxz += __shfl_xor(sxz, off, 16);
        syy += __shfl_xor(syy, off, 16); syz += __shfl_xor(syz, off, 16); szz += __shfl_xor(szz, off, 16);
    }

    if (l16 == 0) {
        const double kinv = 1.0 / (double)KNN;
        double m00 = sxx - sx * sx * kinv;
        double m11 = syy - sy * sy * kinv;
        double m22 = szz - sz * sz * kinv;
        double m01 = sxy - sx * sy * kinv;
        double m02 = sxz - sx * sz * kinv;
        double m12 = syz - sy * sz * kinv;

        double nx = 1.0, ny = 0.0, nz = 0.0;
        double q3 = (m00 + m11 + m22) / 3.0;
        double p1 = m01 * m01 + m02 * m02 + m12 * m12;
        double d00 = m00 - q3, d11 = m11 - q3, d22 = m22 - q3;
        double p2 = d00 * d00 + d11 * d11 + d22 * d22 + 2.0 * p1;
        if (p2 > 1e-280) {
            double pp = sqrt(p2 / 6.0);
            double ip = 1.0 / pp;
            double b00 = d00 * ip, b11 = d11 * ip, b22 = d22 * ip;
            double b01 = m01 * ip, b02 = m02 * ip, b12 = m12 * ip;
            double detB = b00 * (b11 * b22 - b12 * b12)
                        - b01 * (b01 * b22 - b12 * b02)
                        + b02 * (b01 * b12 - b11 * b02);
            double rr = 0.5 * detB;
            rr = rr < -1.0 ? -1.0 : (rr > 1.0 ? 1.0 : rr);
            double phi = acos(rr) / 3.0;
            double lam = q3 + 2.0 * pp * cos(phi + 2.0943951023931953); // smallest eig
            double a00 = m00 - lam, a11 = m11 - lam, a22 = m22 - lam;
            double v0x = m01 * m12 - m02 * a11, v0y = m02 * m01 - a00 * m12, v0z = a00 * a11 - m01 * m01;
            double v1x = m01 * a22 - m02 * m12, v1y = m02 * m02 - a00 * a22, v1z = a00 * m12 - m01 * m02;
            double v2x = a11 * a22 - m12 * m12, v2y = m12 * m02 - m01 * a22, v2z = m01 * m12 - a11 * m02;
            double n0 = v0x * v0x + v0y * v0y + v0z * v0z;
            double n1 = v1x * v1x + v1y * v1y + v1z * v1z;
            double n2 = v2x * v2x + v2y * v2y + v2z * v2z;
            double bx = v0x, by = v0y, bz = v0z, bn = n0;
            if (n1 > bn) { bx = v1x; by = v1y; bz = v1z; bn = n1; }
            if (n2 > bn) { bx = v2x; by = v2y; bz = v2z; bn = n2; }
            if (bn > 1e-280) {
                double inv = 1.0 / sqrt(bn);
                nx = bx * inv; ny = by * inv; nz = bz * inv;
            }
        }
        double dq = -(qx * nx + qy * ny + qz * nz);
        if (dq < 0.0) { nx = -nx; ny = -ny; nz = -nz; }

        float* ob = out + (size_t)b * 6 * N_PTS;
        ob[3 * N_PTS + oi] = (float)nx;
        ob[4 * N_PTS + oi] = (float)ny;
        ob[5 * N_PTS + oi] = (float)nz;
    }
}

// ---------------------------------------------------------------------------
extern "C" void kernel_launch(void* const* d_in, const int* in_sizes, int n_in,
                              void* d_out, int out_size, void* d_ws, size_t ws_size,
                              hipStream_t stream) {
    const float* x = (const float*)d_in[0];
    float* out = (float*)d_out;
    char* ws = (char*)d_ws;
    float4* S    = (float4*)(ws);                 // 512 KB
    int*    O    = (int*)(ws + 524288);           // 128 KB
    int*    bsta = (int*)(ws + 655360);           // 4*4097*4 = 65552 B
    int*    hist = (int*)(ws + 720912);           // 65536 B
    int*    cur  = (int*)(ws + 786448);           // 65536 B

    hipMemsetAsync(hist, 0, 4 * NBKT * sizeof(int), stream);
    hist_kernel<<<dim3(128), dim3(256), 0, stream>>>(x, hist, out);
    scan_kernel<<<dim3(4), dim3(256), 0, stream>>>(hist, bsta, cur);
    scatter_kernel<<<dim3(128), dim3(256), 0, stream>>>(x, S, O, cur);
    knn_normal_kernel<<<dim3(4096), dim3(BLOCK), 0, stream>>>(S, O, bsta, out);
}

// Round 12
// 164.699 us; speedup vs baseline: 1.0588x; 1.0588x over previous
//
#include <hip/hip_runtime.h>
#include <math.h>

#define N_PTS   8192
#define KNN     30
#define CAPG    104     // max stored candidates per group (lambda=48, +8 sigma)
#define STR     105     // LDS row stride in u64
#define GROUPS  8       // queries per block
#define BLOCK   128     // 2 waves per block
#define NZ      64
#define NY      64
#define NBKT    (NZ * NY)
#define CLO     -4.0f
#define CSC     8.0f    // bucket = floor((c - CLO) * CSC)
#define BWID    0.125f  // bucket width
#define LAMBDA  48.0f

// ws: S f4[32768]@0 | O i32[32768]@524288 | bstart i32[4*4097]@655360
//     cur i32[4*4096]@720912

__device__ __forceinline__ int clampi(int v, int lo, int hi) {
    return v < lo ? lo : (v > hi ? hi : v);
}
__device__ __forceinline__ int bucket_of(float pz, float py) {
    int zb = clampi((int)floorf((pz - CLO) * CSC), 0, NZ - 1);
    int yb = clampi((int)floorf((py - CLO) * CSC), 0, NY - 1);
    return (zb << 6) | yb;
}

// ---------------------------------------------------------------------------
// Fused LDS histogram + prefix scan. 4 blocks (one per batch) x 1024.
// No global hist, no memset dispatch.
// ---------------------------------------------------------------------------
__global__ __launch_bounds__(1024) void histscan_kernel(const float* __restrict__ x,
                                                        int* __restrict__ bstart,
                                                        int* __restrict__ cur) {
    __shared__ int hist[NBKT];     // 16 KB
    __shared__ int wtot[16];
    const int b = blockIdx.x, t = threadIdx.x;
    const int lane = t & 63, wid = t >> 6;
    const float* xb = x + (size_t)b * 3 * N_PTS;

    for (int k = t; k < NBKT; k += 1024) hist[k] = 0;
    __syncthreads();
    #pragma unroll
    for (int u = 0; u < 8; ++u) {
        int i = (u << 10) + t;
        float py = xb[N_PTS + i], pz = xb[2 * N_PTS + i];
        atomicAdd(&hist[bucket_of(pz, py)], 1);
    }
    __syncthreads();

    // scan: thread owns 4 buckets
    int base = t << 2;
    int l0 = hist[base], l1 = hist[base + 1], l2 = hist[base + 2], l3 = hist[base + 3];
    int s = l0 + l1 + l2 + l3;
    int sum = s;
    #pragma unroll
    for (int off = 1; off < 64; off <<= 1) {
        int v = __shfl_up(sum, off);
        if (lane >= off) sum += v;
    }
    if (lane == 63) wtot[wid] = sum;
    __syncthreads();
    int wbase = 0;
    #pragma unroll
    for (int k = 0; k < 16; ++k) wbase += (k < wid) ? wtot[k] : 0;
    int run = wbase + sum - s;                    // exclusive prefix
    int* bsb = bstart + b * (NBKT + 1);
    int* curb = cur + b * NBKT;
    bsb[base]     = run; curb[base]     = run; run += l0;
    bsb[base + 1] = run; curb[base + 1] = run; run += l1;
    bsb[base + 2] = run; curb[base + 2] = run; run += l2;
    bsb[base + 3] = run; curb[base + 3] = run;
    if (t == 1023) bsb[NBKT] = N_PTS;
}

// ---------------------------------------------------------------------------
// Counting-sort scatter + out ch0..2 copy (xx_np = bitwise-numpy |p|^2).
// 128 blocks x 256.
// ---------------------------------------------------------------------------
__global__ __launch_bounds__(256) void scatter_kernel(const float* __restrict__ x,
                                                      float4* __restrict__ S,
                                                      int* __restrict__ O,
                                                      int* __restrict__ cur,
                                                      float* __restrict__ out) {
    int gid = blockIdx.x * 256 + threadIdx.x;     // 0..32767
    int b = gid >> 13, i = gid & (N_PTS - 1);
    const float* xb = x + (size_t)b * 3 * N_PTS;
    float px = xb[i], py = xb[N_PTS + i], pz = xb[2 * N_PTS + i];
    float* ob = out + (size_t)b * 6 * N_PTS;
    ob[i]             = px;
    ob[N_PTS + i]     = py;
    ob[2 * N_PTS + i] = pz;
    float xx = __fadd_rn(__fadd_rn(__fmul_rn(px, px), __fmul_rn(py, py)),
                         __fmul_rn(pz, pz));
    int dst = atomicAdd(&cur[b * NBKT + bucket_of(pz, py)], 1);
    S[(b << 13) + dst] = make_float4(px, py, pz, xx);
    O[(b << 13) + dst] = i;
}

// ---------------------------------------------------------------------------
// Main: 16 lanes/query, 8 CONSECUTIVE queries/block, x1031 block swizzle
// (locality within block + flattened tail across dispatch). Elliptical
// per-z-row y-windows; ballot-compact u64 keys; register-key inverted rank.
// ---------------------------------------------------------------------------
__global__ __launch_bounds__(BLOCK, 6) void knn_normal_kernel(const float4* __restrict__ S,
                                                              const int* __restrict__ O,
                                                              const int* __restrict__ bstart,
                                                              float* __restrict__ out) {
    __shared__ unsigned long long ldk[GROUPS * STR];

    const int t    = threadIdx.x;
    const int l16  = t & 15;
    const int g    = t >> 4;
    const int gsh  = (t & 63) & ~15;
    const int qblk = (blockIdx.x * 1031) & 4095;  // bijective swizzle
    const int qid  = qblk * GROUPS + g;           // 8 consecutive queries per block
    const int b    = qid >> 13;
    const int pos  = qid & (N_PTS - 1);
    const float4* __restrict__ P  = S + ((size_t)b << 13);
    const int*    __restrict__ Ob = O + ((size_t)b << 13);
    const int*    __restrict__ bs = bstart + b * (NBKT + 1);
    const float4 qp = P[pos];
    const int    oi = Ob[pos];

    unsigned long long* __restrict__ ldg = ldk + g * STR;

    // ---- radius: solve lambda(r)=48 (Gaussian ball mass), lane-parallel Simpson-9
    const float c = fmaxf(sqrtf(qp.w), 1e-3f);
    float rlo = 0.05f, rhi = 6.0f;
    for (int it = 0; it < 14; ++it) {
        float r = 0.5f * (rlo + rhi);
        float slo = fmaxf(c - r, 0.0f);
        float h = (c + r - slo) * 0.125f;
        float f = 0.0f;
        if (l16 <= 8) {
            float sq = slo + h * (float)l16;
            float cs = c - sq;
            float hh = fmaxf(fminf((r * r - cs * cs) * (0.5f / c), 2.0f * sq), 0.0f);
            float w = (l16 == 0 || l16 == 8) ? 1.0f : ((l16 & 1) ? 4.0f : 2.0f);
            f = w * __expf(-0.5f * sq * sq) * sq * hh;
        }
        f += __shfl_xor(f, 1, 16); f += __shfl_xor(f, 2, 16);
        f += __shfl_xor(f, 4, 16); f += __shfl_xor(f, 8, 16);
        float lam = 1089.3f * f * h;       // 520.1 * 2*pi / 3
        if (lam < LAMBDA) rlo = r; else rhi = r;
    }
    float rad = rhi * 1.02f;
    float r2  = rad * rad;

    int  cnt = 0;
    bool active = true;

    for (;;) {
        if (active) {
            cnt = 0;
            float w  = __fmaf_rn(sqrtf(r2), 1.002f, 1e-3f);   // guard band
            float w2 = w * w;
            int zlo = clampi((int)floorf((qp.z - w - CLO) * CSC), 0, NZ - 1);
            int zhi = clampi((int)floorf((qp.z + w - CLO) * CSC), 0, NZ - 1);
            for (int zb = zlo; zb <= zhi; ++zb) {
                // conservative distance from qz to this z-row's nominal interval
                float rz0 = CLO + (float)zb * BWID;
                float dz  = fmaxf(fmaxf(rz0 - qp.z, qp.z - (rz0 + BWID)), 0.0f);
                float yw  = sqrtf(fmaxf(w2 - dz * dz, 0.0f));
                int ylo = clampi((int)floorf((qp.y - yw - CLO) * CSC), 0, NY - 1);
                int yhi = clampi((int)floorf((qp.y + yw - CLO) * CSC), 0, NY - 1);
                int lo = bs[(zb << 6) + ylo];
                int hi = bs[(zb << 6) + yhi + 1];
                int smax = (hi - lo + 31) >> 5;   // group-uniform, 32 cand/iter
                for (int s = 0; s < smax; ++s) {
                    int j1  = lo + (s << 5) + l16;
                    int j2  = j1 + 16;
                    int jc1 = j1 < hi ? j1 : hi - 1;
                    int jc2 = j2 < hi ? j2 : hi - 1;
                    float4 p1 = P[jc1];
                    float4 p2 = P[jc2];
                    // bitwise numpy-fp32 pairwise distances
                    float mm1 = __fmaf_rn(qp.z, p1.z, __fmaf_rn(qp.y, p1.y, __fmul_rn(qp.x, p1.x)));
                    float d1  = __fsub_rn(__fadd_rn(qp.w, p1.w), __fmul_rn(2.0f, mm1));
                    float mm2 = __fmaf_rn(qp.z, p2.z, __fmaf_rn(qp.y, p2.y, __fmul_rn(qp.x, p2.x)));
                    float d2  = __fsub_rn(__fadd_rn(qp.w, p2.w), __fmul_rn(2.0f, mm2));
                    bool hit1 = (j1 < hi) && (d1 <= r2);
                    bool hit2 = (j2 < hi) && (d2 <= r2);
                    unsigned long long m1 = __ballot(hit1);
                    unsigned sub1 = (unsigned)((m1 >> gsh) & 0xFFFFull);
                    if (hit1) {
                        int slot = cnt + __popc(sub1 & ((1u << l16) - 1u));
                        if (slot < CAPG) {
                            unsigned u = __float_as_uint(d1);
                            u = (u & 0x80000000u) ? ~u : (u | 0x80000000u);
                            ldg[slot] = ((unsigned long long)u << 28) | (unsigned long long)jc1;
                        }
                    }
                    cnt += __popc(sub1);
                    unsigned long long m2 = __ballot(hit2);
                    unsigned sub2 = (unsigned)((m2 >> gsh) & 0xFFFFull);
                    if (hit2) {
                        int slot = cnt + __popc(sub2 & ((1u << l16) - 1u));
                        if (slot < CAPG) {
                            unsigned u = __float_as_uint(d2);
                            u = (u & 0x80000000u) ? ~u : (u | 0x80000000u);
                            ldg[slot] = ((unsigned long long)u << 28) | (unsigned long long)jc2;
                        }
                    }
                    cnt += __popc(sub2);
                }
            }
        }
        bool bad = active && (cnt < KNN || cnt > CAPG);
        if (__ballot(bad) == 0ULL) break;         // wave-uniform exit
        active = bad;
        if (active) r2 = (cnt < KNN) ? r2 * 1.6f : r2 * 0.82f;
    }

    // fill orig-idx field (bits 14..27) and keep own keys in registers
    unsigned long long mykey[7];
    #pragma unroll
    for (int m = 0; m < 7; ++m) mykey[m] = ~0ULL;
    {
        int nk = 0;
        for (int k = l16; k < cnt; k += 16) {
            unsigned long long key = ldg[k];
            int jc = (int)(key & 0x3FFFull);
            key = (key & ~0x0FFFFFFFull) | ((unsigned long long)Ob[jc] << 14)
                | (unsigned long long)jc;
            ldg[k] = key;
            mykey[nk++] = key;
        }
    }
    __syncthreads();

    // ---- stable top-30: inverted rank — one broadcast LDS read per union key,
    //      7 independent register compares (u64 order == lex (d, orig idx))
    int rank0 = 0, rank1 = 0, rank2 = 0, rank3 = 0, rank4 = 0, rank5 = 0, rank6 = 0;
    for (int u = 0; u < cnt; ++u) {
        unsigned long long ku = ldg[u];
        rank0 += (ku < mykey[0]) ? 1 : 0;
        rank1 += (ku < mykey[1]) ? 1 : 0;
        rank2 += (ku < mykey[2]) ? 1 : 0;
        rank3 += (ku < mykey[3]) ? 1 : 0;
        rank4 += (ku < mykey[4]) ? 1 : 0;
        rank5 += (ku < mykey[5]) ? 1 : 0;
        rank6 += (ku < mykey[6]) ? 1 : 0;
    }
    int rank[7] = { rank0, rank1, rank2, rank3, rank4, rank5, rank6 };

    const double qx = (double)qp.x, qy = (double)qp.y, qz = (double)qp.z;
    double sx = 0.0, sy = 0.0, sz = 0.0;
    double sxx = 0.0, sxy = 0.0, sxz = 0.0, syy = 0.0, syz = 0.0, szz = 0.0;

    #pragma unroll
    for (int m = 0; m < 7; ++m) {
        if (rank[m] < KNN) {                      // exactly 30 survivors per group
            float4 p = P[(int)(mykey[m] & 0x3FFFull)];
            double ax = (double)p.x - qx, ay = (double)p.y - qy, az = (double)p.z - qz;
            sx += ax; sy += ay; sz += az;
            sxx = fma(ax, ax, sxx); sxy = fma(ax, ay, sxy); sxz = fma(ax, az, sxz);
            syy = fma(ay, ay, syy); syz = fma(ay, az, syz); szz = fma(az, az, szz);
        }
    }

    #pragma unroll
    for (int off = 1; off < 16; off <<= 1) {
        sx  += __shfl_xor(sx,  off, 16); sy  += __shfl_xor(sy,  off, 16); sz  += __shfl_xor(sz,  off, 16);
        sxx += __shfl_xor(sxx, off, 16); sxy += __shfl_xor(sxy, off, 16); sxz += __shfl_xor(sxz, off, 16);
        syy += __shfl_xor(syy, off, 16); syz += __shfl_xor(syz, off, 16); szz += __shfl_xor(szz, off, 16);
    }

    if (l16 == 0) {
        const double kinv = 1.0 / (double)KNN;
        double m00 = sxx - sx * sx * kinv;
        double m11 = syy - sy * sy * kinv;
        double m22 = szz - sz * sz * kinv;
        double m01 = sxy - sx * sy * kinv;
        double m02 = sxz - sx * sz * kinv;
        double m12 = syz - sy * sz * kinv;

        double nx = 1.0, ny = 0.0, nz = 0.0;
        double q3 = (m00 + m11 + m22) / 3.0;
        double p1 = m01 * m01 + m02 * m02 + m12 * m12;
        double d00 = m00 - q3, d11 = m11 - q3, d22 = m22 - q3;
        double p2 = d00 * d00 + d11 * d11 + d22 * d22 + 2.0 * p1;
        if (p2 > 1e-280) {
            double pp = sqrt(p2 / 6.0);
            double ip = 1.0 / pp;
            double b00 = d00 * ip, b11 = d11 * ip, b22 = d22 * ip;
            double b01 = m01 * ip, b02 = m02 * ip, b12 = m12 * ip;
            double detB = b00 * (b11 * b22 - b12 * b12)
                        - b01 * (b01 * b22 - b12 * b02)
                        + b02 * (b01 * b12 - b11 * b02);
            double rr = 0.5 * detB;
            rr = rr < -1.0 ? -1.0 : (rr > 1.0 ? 1.0 : rr);
            double phi = acos(rr) / 3.0;
            double lam = q3 + 2.0 * pp * cos(phi + 2.0943951023931953); // smallest eig
            double a00 = m00 - lam, a11 = m11 - lam, a22 = m22 - lam;
            double v0x = m01 * m12 - m02 * a11, v0y = m02 * m01 - a00 * m12, v0z = a00 * a11 - m01 * m01;
            double v1x = m01 * a22 - m02 * m12, v1y = m02 * m02 - a00 * a22, v1z = a00 * m12 - m01 * m02;
            double v2x = a11 * a22 - m12 * m12, v2y = m12 * m02 - m01 * a22, v2z = m01 * m12 - a11 * m02;
            double n0 = v0x * v0x + v0y * v0y + v0z * v0z;
            double n1 = v1x * v1x + v1y * v1y + v1z * v1z;
            double n2 = v2x * v2x + v2y * v2y + v2z * v2z;
            double bx = v0x, by = v0y, bz = v0z, bn = n0;
            if (n1 > bn) { bx = v1x; by = v1y; bz = v1z; bn = n1; }
            if (n2 > bn) { bx = v2x; by = v2y; bz = v2z; bn = n2; }
            if (bn > 1e-280) {
                double inv = 1.0 / sqrt(bn);
                nx = bx * inv; ny = by * inv; nz = bz * inv;
            }
        }
        double dq = -(qx * nx + qy * ny + qz * nz);
        if (dq < 0.0) { nx = -nx; ny = -ny; nz = -nz; }

        float* ob = out + (size_t)b * 6 * N_PTS;
        ob[3 * N_PTS + oi] = (float)nx;
        ob[4 * N_PTS + oi] = (float)ny;
        ob[5 * N_PTS + oi] = (float)nz;
    }
}

// ---------------------------------------------------------------------------
extern "C" void kernel_launch(void* const* d_in, const int* in_sizes, int n_in,
                              void* d_out, int out_size, void* d_ws, size_t ws_size,
                              hipStream_t stream) {
    const float* x = (const float*)d_in[0];
    float* out = (float*)d_out;
    char* ws = (char*)d_ws;
    float4* S    = (float4*)(ws);                 // 512 KB
    int*    O    = (int*)(ws + 524288);           // 128 KB
    int*    bsta = (int*)(ws + 655360);           // 4*4097*4 = 65552 B
    int*    cur  = (int*)(ws + 720912);           // 65536 B

    histscan_kernel<<<dim3(4), dim3(1024), 0, stream>>>(x, bsta, cur);
    scatter_kernel<<<dim3(128), dim3(256), 0, stream>>>(x, S, O, cur, out);
    knn_normal_kernel<<<dim3(4096), dim3(BLOCK), 0, stream>>>(S, O, bsta, out);
}